// Round 8
// baseline (272.850 us; speedup 1.0000x reference)
//
#include <hip/hip_runtime.h>

// Soft-DTW gradient, batch=64, 256x256, gamma=0.01 — forward/backward-DP form.
// R22 = R21 (f64 linear DP) + SKEW-FOLDED V-PLANE LAYOUT (coalesced stores).
// Ledger: per-body ~3500-4000cy invariant under sync structure (R15/16),
// reg budget (R17), on-chain transcendentals (R20), load placement (R20),
// waitcnt choice (R21); VALU issue only ~600-900cy/body. Remaining shared
// trait: vmem CACHELINE FANOUT. Lane L owns rows 4L..4L+3 -> every
// load/store has ~4KB lane stride = 64 lines/instr; 8 instrs = 512
// line-transactions/body/wave. At ~6-7cy/line (TCP line-slot throughput,
// single wave): R21 512*7=3580cy ✓ matches; R15 384*6=2300 ✓. Fix: V-plane
// layout [m&63][r][L][cc] — the (m,L) diamond folds bijectively into 64
// slots (m<=62 has L<=m; m>=64 has L>=m-63; disjoint) — body-m stores are
// lane-contiguous 1KB = 16 lines/instr. Body lines 512 -> 320.
// Epilogue reads skewed planes coalesced; theta is folded OUT of the
// epilogue: F-plane stores F'' = V' - K2*th (log of 3-neighbor sum BEFORE
// the p-factor, PREMUL=true), B-plane stores full B'. Then
// E = exp2(K2*th + Ftot - F' - B') = exp2(Ftot - F'' - B') with
// Ftot = F''(M,N) + K2*th(M,N) (one corner load per plane).
// Rest identical to R21: f64 linear cells (W = 2^(-K2 th) * (Wl+Wd+Wu),
// per-lane frame S, one anchor/body), asm-pinned loads + vmcnt peel
// 16/8/12, one wave/block, 64 lanes, R=4, skew m=g+L, shuffle exchange,
// 128 blocks (0..63 F, 64..127 B reversed), device flag barrier.
// ws: F'' planes [64][65536] f32 (skewed), B' planes (skewed), counter u32.

#define MM 256
#define NN 256
#define R 4              // rows per lane
#define NB 64            // batch elements
#define NBLK 128         // DP blocks: 64 forward + 64 backward
#define K2   144.269504089f     // 1/(gamma*ln2) = (1/gamma)*log2(e)
#define TB64 1700        // target biased exponent (f64) for frame anchor

typedef float f32x4 __attribute__((ext_vector_type(4)));

__device__ __forceinline__ int iclamp(int x, int lo, int hi) {
    return x < lo ? lo : (x > hi ? hi : x);
}
__device__ __forceinline__ int imax(int a, int b) { return a > b ? a : b; }
// f64 biased exponent; 0 for zero/denormal (treated as dead).
__device__ __forceinline__ int bexp64(double x) {
    return (int)(((unsigned long long)__double_as_longlong(x) >> 52) & 2047u);
}
// reconciled exponent of a foreign-frame value (dead contributes 0).
__device__ __forceinline__ int rexp64(double x, int d) {
    const int e = bexp64(x);
    return e == 0 ? 0 : e + d;
}

// One soft-DTW DP over the virtual matrix, f64 linear domain.
// REV=false: virtual == physical (computes F). REV=true: virtual (i,j) =
// physical (255-i,255-j) (computes B in its own virtual skew layout).
// PREMUL=true: store V'' = S - log2(Wl+Wd+Wu)  (no theta term, for F).
// PREMUL=false: store V'  = S - log2(p*(Wl+Wd+Wu))  (full value, for B).
// Store layout: plane[(m&63)][r][L][cc] floats — lane-contiguous per body.
template<bool REV, bool PREMUL>
__device__ __forceinline__ void run_dp(const float* __restrict__ th,
                                       float* __restrict__ Vp)
{
    const int L = threadIdx.x;                      // 0..63

    double up[R];                // own rows' right-edge u (frame S)
    double rcv[4];               // neighbor bottom row (frame recS)
    double bot[4];               // own bottom row to send (frame S)
    double prevW = 0.0;          // top-left diag value (frame prevWS)
    #pragma unroll
    for (int r = 0; r < R; ++r) up[r] = 0.0;
    #pragma unroll
    for (int j = 0; j < 4; ++j) { rcv[j] = 0.0; bot[j] = 0.0; }
    int S = 0, recS = 0, prevWS = 0;
    f32x4 thB[3][R];
    #pragma unroll
    for (int p = 0; p < 3; ++p)
        #pragma unroll
        for (int r = 0; r < R; ++r) thB[p][r] = (f32x4)0.0f;

    auto body = [&](const int LD, const int CU, const int m, const int WN) {
        const int g = m - L;
        const int gl = iclamp(g + 2, 0, 63);        // prefetch distance 2
        #pragma unroll
        for (int r = 0; r < R; ++r) {
            const int vr = 4 * L + r;
            const float* addr = REV ? (th + (255 - vr) * NN + (252 - 4 * gl))
                                    : (th + vr * NN + 4 * gl);
            asm volatile("global_load_dwordx4 %0, %1, off"
                         : "=v"(thB[LD][r]) : "v"(addr));
        }
        // Counted wait (every body; in-order vmcnt arithmetic). WN is a
        // call-site literal -> constant-folds after inlining.
        if (WN == 8)       asm volatile("s_waitcnt vmcnt(8)"  ::: "memory");
        else if (WN == 12) asm volatile("s_waitcnt vmcnt(12)" ::: "memory");
        else               asm volatile("s_waitcnt vmcnt(16)" ::: "memory");
        __builtin_amdgcn_sched_barrier(0);

        if ((unsigned)g <= 63u) {
            // ---- per-body anchor: reconcile frames, center max at TB64 ----
            const int drec = S - recS, dpw = S - prevWS;
            int em = bexp64(up[0]);
            em = imax(em, bexp64(up[1])); em = imax(em, bexp64(up[2]));
            em = imax(em, bexp64(up[3]));
            em = imax(em, rexp64(rcv[0], drec)); em = imax(em, rexp64(rcv[1], drec));
            em = imax(em, rexp64(rcv[2], drec)); em = imax(em, rexp64(rcv[3], drec));
            em = imax(em, rexp64(prevW, dpw));
            if (g == 0 && L == 0) em = imax(em, 1023 + S);   // corner seed
            const int k0 = em - TB64;
            S -= k0;
            #pragma unroll
            for (int j = 0; j < 4; ++j) rcv[j] = ldexp(rcv[j], drec - k0);
            prevW = ldexp(prevW, dpw - k0);
            #pragma unroll
            for (int r = 0; r < R; ++r) up[r] = ldexp(up[r], -k0);
            const double ud0 = (g == 0) ? ((L == 0) ? ldexp(1.0, S) : 0.0)
                                        : prevW;

            // ---- 4 columns x 4 rows, f64 linear cells ----
            float vbuf[R][4];
            #pragma unroll
            for (int cc = 0; cc < 4; ++cc) {
                // off-chain: p = 2^(-K2*th) as exact f64
                double pdc[R];
                #pragma unroll
                for (int r = 0; r < R; ++r) {
                    const float thv = thB[CU][r][REV ? 3 - cc : cc];
                    const float f  = -K2 * thv;
                    const float fi = rintf(f);
                    pdc[r] = ldexp((double)exp2f(f - fi), (int)fi);
                }
                // off-chain: pre[r] = diag + left (both previous-col values)
                double pre[R];
                pre[0] = ((cc == 0) ? ud0 : rcv[cc - 1]) + up[0];
                #pragma unroll
                for (int r = 1; r < R; ++r) pre[r] = up[r - 1] + up[r];
                double vu = rcv[cc];
                #pragma unroll
                for (int r = 0; r < R; ++r) {
                    const double s3 = pre[r] + vu;              // the chain
                    const double un = pdc[r] * s3;              // the chain
                    // store path (off-chain): V = (S - e) - log2(mant)
                    const double sv = PREMUL ? s3 : un;
                    const long long ub = __double_as_longlong(sv);
                    const int ef = (int)(((unsigned long long)ub >> 52) & 2047u);
                    const double mant = __longlong_as_double(
                        (ub & 0x000FFFFFFFFFFFFFLL) | 0x3FF0000000000000LL);
                    vbuf[r][cc] = (ef == 0)
                        ? __builtin_inff()
                        : ((float)(S - (ef - 1023)) - log2f((float)mant));
                    if (r == R - 1) bot[cc] = un;
                    vu = un; up[r] = un;
                }
            }
            recS = S;            // rcv now lives in frame S
            // ---- coalesced skew-fold store: plane[(m&63)][r][L][cc] ----
            float* dst = Vp + ((m & 63) << 10) + (L << 2);
            #pragma unroll
            for (int r = 0; r < R; ++r) {
                f32x4 sv4 = {vbuf[r][0], vbuf[r][1], vbuf[r][2], vbuf[r][3]};
                *(f32x4*)(dst + (r << 8)) = sv4;
            }
        }
        // ---- in-wave exchange: lane L receives lane L-1's bottom + frame ----
        const double nb0 = __shfl_up(bot[0], 1);
        const double nb1 = __shfl_up(bot[1], 1);
        const double nb2 = __shfl_up(bot[2], 1);
        const double nb3 = __shfl_up(bot[3], 1);
        const int   nbS = __shfl_up(S, 1);
        prevW = rcv[3]; prevWS = recS;              // old rcv.w -> next diag
        rcv[0] = nb0; rcv[1] = nb1; rcv[2] = nb2; rcv[3] = nb3; recS = nbS;
        if (L == 0) { rcv[0] = rcv[1] = rcv[2] = rcv[3] = 0.0; recS = S; }
    };
    // Warm-up peel: bodies 0,1 issue loads only (no stores); from L2 on,
    // vmcnt(16) drains exactly S_{k-3} + L_{k-2}.
    body(0, 1, -2, 16);
    body(1, 2, -1, 16);
    body(2, 0,  0,  8);
    body(0, 1,  1, 12);
    body(1, 2,  2, 16);
    body(2, 0,  3, 16);
    for (int k = 6; k < 129; k += 3) {              // m = 4 .. 126
        body(0, 1, k - 2, 16);
        body(1, 2, k - 1, 16);
        body(2, 0, k,     16);
    }
}

__global__ __launch_bounds__(64, 1) void dtw_fb(
    const float* __restrict__ D,
    float* __restrict__ out,          // [256][256]
    float* __restrict__ ws)
{
    const int blk = blockIdx.x;
    const bool rev = blk >= NB;
    const int b = rev ? blk - NB : blk;
    const float* __restrict__ th = D + (size_t)b * (MM * NN);
    float* __restrict__ Fp = ws + (size_t)b * (MM * NN);
    float* __restrict__ Bp = ws + (size_t)(NB + b) * (MM * NN);
    unsigned* ctr = (unsigned*)(ws + (size_t)2 * NB * (MM * NN));

    if (rev) run_dp<true , false>(th, Bp);   // B: full V' (with theta)
    else     run_dp<false, true >(th, Fp);   // F: V'' (pre-multiply, no theta)

    // ---------------- device-scope barrier (128 blocks, 1 wave each) ----------------
    __threadfence();                   // release V-plane stores (L2 writeback)
    if (threadIdx.x == 0)
        __hip_atomic_fetch_add(ctr, 1u, __ATOMIC_ACQ_REL, __HIP_MEMORY_SCOPE_AGENT);
    unsigned cnt;
    do {
        cnt = __hip_atomic_load(ctr, __ATOMIC_ACQUIRE, __HIP_MEMORY_SCOPE_AGENT);
        if (cnt < NBLK) __builtin_amdgcn_s_sleep(2);
    } while (cnt < NBLK);
    __builtin_amdgcn_fence(__ATOMIC_ACQUIRE, "agent");   // invalidate caches

    // ---------------- fused epilogue + batch mean (skew-space iteration) ---
    // E_b(i,j) = exp2( Ftot_b - F''_b(i,j) - B'_b(i,j) ),
    // Ftot_b = F''_b(M,N) + K2*th_b(M,N)  (theta folded out of the loop).
    // Thread owns 2 float4s in F-skew a-space (coalesced F reads); B-plane
    // read at the mirrored virtual address (reversed-contiguous, coalesced).
    // F corner (virt 255,255): m=126 -> a = 62*1024 + 3*256 + 63*4 + 3 = 64511.
    {
        const int t = threadIdx.x;
        const float inv = 1.0f / (float)NB;
        #pragma unroll
        for (int q = 0; q < 2; ++q) {
            const int a4 = blk * 128 + q * 64 + t;          // 0..16383
            const int a  = a4 << 2;
            const int mfold = a >> 10;
            const int rr = (a >> 8) & 3;
            const int Lx = (a >> 2) & 63;
            const int m  = (Lx <= mfold) ? mfold : mfold + 64;
            const int g  = m - Lx;
            const int i  = 4 * Lx + rr;
            const int j4 = 4 * g;
            const int mB = 126 - m;
            const int aB = ((mB & 63) << 10) + ((3 - rr) << 8) + ((63 - Lx) << 2);
            float4 acc = make_float4(0.f, 0.f, 0.f, 0.f);
            for (int p = 0; p < NB; ++p) {
                const float* __restrict__ fp = ws + (size_t)p * (MM * NN);
                const float* __restrict__ bp = ws + (size_t)(NB + p) * (MM * NN);
                const float Ft = fp[64511] + K2 * D[(size_t)p * (MM * NN) + 65535];
                const float4 f4 = *(const float4*)(fp + a);
                const float4 b4 = *(const float4*)(bp + aB);  // jj reversed
                acc.x += exp2f(Ft - f4.x - b4.w);
                acc.y += exp2f(Ft - f4.y - b4.z);
                acc.z += exp2f(Ft - f4.z - b4.y);
                acc.w += exp2f(Ft - f4.w - b4.x);
            }
            out[i * NN + j4 + 0] = acc.x * inv;
            out[i * NN + j4 + 1] = acc.y * inv;
            out[i * NN + j4 + 2] = acc.z * inv;
            out[i * NN + j4 + 3] = acc.w * inv;
        }
    }
}

extern "C" void kernel_launch(void* const* d_in, const int* in_sizes, int n_in,
                              void* d_out, int out_size, void* d_ws, size_t ws_size,
                              hipStream_t stream) {
    const float* D = (const float*)d_in[0];
    float* out = (float*)d_out;
    float* ws = (float*)d_ws;

    // zero the barrier counter (ws is re-poisoned 0xAA before every launch)
    hipMemsetAsync(ws + (size_t)2 * NB * (MM * NN), 0, sizeof(unsigned), stream);
    dtw_fb<<<dim3(NBLK), dim3(64), 0, stream>>>(D, out, ws);
}